// Round 2
// baseline (971.868 us; speedup 1.0000x reference)
//
#include <hip/hip_runtime.h>
#include <hip/hip_cooperative_groups.h>
#include <math.h>

namespace cg = cooperative_groups;

#define B 32
#define N 16384
#define M 128
#define D 1024
#define L 390   // 3*M+6
#define EPSF 1e-16f

#define GRID  1024
#define BPB   (GRID / B)        // 32 blocks per batch
#define CHUNK (N / BPB)         // 512 rows per block

// ws layout (floats):
//   [O_OFF,  O_OFF+B*L)   o = emb@W + b
//   [P_OFF,  P_OFF+B*8)   per-batch params {beta,g,s0,s1,s2,gamma,knorm,pad}
//   [S1_OFF, +B)          sum exp(z)   (atomic)
//   [S2_OFF, +B)          sum w_sh     (atomic)
//   [Z_OFF,  +B*N)        u = exp(beta*sim)
#define O_OFF  0
#define P_OFF  (B*L)
#define S1_OFF (P_OFF + B*8)
#define S2_OFF (S1_OFF + B)
#define Z_OFF  (S2_OFF + B)

typedef float fvec4 __attribute__((ext_vector_type(4)));

__device__ __forceinline__ float softplusf(float x) {
    return x > 20.f ? x : log1pf(expf(x));
}
__device__ __forceinline__ float sigmoidf(float x) {
    return 1.f / (1.f + expf(-x));
}

// ===========================================================================
// Fused cooperative kernel: all 5 stages, 3 grid syncs.
// grid(1024) x 256 thr, 4 blocks/CU guaranteed by __launch_bounds__(256,4).
// Block blk owns batch b = blk/32, rows [n0, n0+512) with n0 = (blk%32)*512.
// ===========================================================================
__global__ __launch_bounds__(256, 4) void fused_all(
    const float* __restrict__ emb, const float* __restrict__ w_prev,
    const float* __restrict__ mem, const float* __restrict__ Wm,
    const float* __restrict__ bias, float* __restrict__ ws,
    float* __restrict__ out)
{
    cg::grid_group gg = cg::this_grid();
    __shared__ float sm[D];          // phase0: emb;  phaseA: k;  phaseC: e|a
    __shared__ float oS[L];
    __shared__ float sred[8];
    const int t    = threadIdx.x;
    const int blk  = blockIdx.x;
    const int wave = t >> 6, lane = t & 63;

    // ---- Phase 0: blocks 0..B-1 compute o[b,:] + per-batch params ----
    if (blk < B) {
        const int b = blk;
        for (int i = t; i < D; i += 256) sm[i] = emb[b * D + i];
        __syncthreads();
        for (int l = t; l < L; l += 256) {
            float acc = 0.f;
            const float* wp = Wm + l;
            #pragma unroll 8
            for (int d = 0; d < D; ++d) acc = fmaf(sm[d], wp[(size_t)d * L], acc);
            acc += bias[l];
            ws[O_OFF + b * L + l] = acc;
            oS[l] = acc;
        }
        __syncthreads();
        if (t < 128) {                         // ||k||: reduce o[0:128]^2
            float kv = oS[t];
            float sq = kv * kv;
            #pragma unroll
            for (int off = 32; off >= 1; off >>= 1) sq += __shfl_xor(sq, off, 64);
            if ((t & 63) == 0) sred[t >> 6] = sq;
        }
        __syncthreads();
        if (t == 0) {
            float knorm = sqrtf(sred[0] + sred[1]);
            float beta  = softplusf(oS[M]);
            float g     = sigmoidf(oS[M + 1]);
            float x0 = oS[M + 2], x1 = oS[M + 3], x2 = oS[M + 4];
            float mx = fmaxf(x0, fmaxf(x1, x2));
            float e0 = expf(x0 - mx), e1 = expf(x1 - mx), e2 = expf(x2 - mx);
            float inv = 1.f / (e0 + e1 + e2);
            float gamma = 1.f + softplusf(oS[M + 5]);
            float* p = ws + P_OFF + b * 8;
            p[0] = beta; p[1] = g; p[2] = e0 * inv; p[3] = e1 * inv; p[4] = e2 * inv;
            p[5] = gamma; p[6] = knorm;
            ws[S1_OFF + b] = 0.f;
            ws[S2_OFF + b] = 0.f;
        }
    }
    gg.sync();

    const int b  = blk / BPB;
    const int n0 = (blk % BPB) * CHUNK;
    float* u = ws + Z_OFF + (size_t)b * N;

    // ---- Phase A: u[n] = exp(beta*cos_sim(mem[n],k)); S1 += sum ----
    if (t < M) sm[t] = ws[O_OFF + b * L + t];
    __syncthreads();
    {
        const float beta  = ws[P_OFF + b * 8 + 0];
        const float knorm = ws[P_OFF + b * 8 + 6];
        const int seg = (lane & 15) * 8;       // 16 lanes x 8 floats per row
        const fvec4 ka = *(const fvec4*)&sm[seg];
        const fvec4 kb = *(const fvec4*)&sm[seg + 4];
        float lsum = 0.f;
        #pragma unroll 4
        for (int it = 0; it < CHUNK / 16; ++it) {      // 4 rows/wave/iter
            const int n = n0 + wave * (CHUNK / 4) + it * 4 + (lane >> 4);
            const float* mp = mem + ((size_t)b * N + n) * M + seg;
            const fvec4 ma = *(const fvec4*)mp;
            const fvec4 mb = *(const fvec4*)(mp + 4);
            float dot = ma.x*ka.x + ma.y*ka.y + ma.z*ka.z + ma.w*ka.w
                      + mb.x*kb.x + mb.y*kb.y + mb.z*kb.z + mb.w*kb.w;
            float sq  = ma.x*ma.x + ma.y*ma.y + ma.z*ma.z + ma.w*ma.w
                      + mb.x*mb.x + mb.y*mb.y + mb.z*mb.z + mb.w*mb.w;
            #pragma unroll
            for (int off = 1; off <= 8; off <<= 1) {
                dot += __shfl_xor(dot, off, 64);
                sq  += __shfl_xor(sq,  off, 64);
            }
            if ((lane & 15) == 0) {
                const float sim = dot / (sqrtf(sq) * knorm + EPSF);
                const float uu  = expf(beta * sim);
                u[n] = uu;
                lsum += uu;
            }
        }
        lsum += __shfl_xor(lsum, 16, 64);
        lsum += __shfl_xor(lsum, 32, 64);
        if (lane == 0) sred[wave] = lsum;
        __syncthreads();
        if (t == 0) atomicAdd(ws + S1_OFF + b, sred[0] + sred[1] + sred[2] + sred[3]);
    }
    gg.sync();

    // ---- Phase B: w_sh = (s0*wg(n-1)+s1*wg(n)+s2*wg(n+1))^gamma; S2 += sum ----
    {
        const float* p = ws + P_OFF + b * 8;
        const float g = p[1], s0 = p[2], s1v = p[3], s2v = p[4], gamma = p[5];
        const float invS1 = 1.f / ws[S1_OFF + b];
        const float gi = g * invS1, gm1 = 1.f - g;
        const float* wp = w_prev + (size_t)b * N;
        float ls = 0.f;
        #pragma unroll
        for (int k2 = 0; k2 < CHUNK / 256; ++k2) {
            const int n  = n0 + k2 * 256 + t;
            const int nm = (n == 0)     ? N - 1 : n - 1;
            const int np = (n == N - 1) ? 0     : n + 1;
            const float wgm = gi * u[nm] + gm1 * wp[nm];
            const float wg0 = gi * u[n ] + gm1 * wp[n ];
            const float wgp = gi * u[np] + gm1 * wp[np];
            const float wt  = s0 * wgm + s1v * wg0 + s2v * wgp;
            const float v = powf(wt, gamma);
            out[(size_t)b * N + n] = v;        // stash w_sh
            ls += v;
        }
        #pragma unroll
        for (int off = 32; off >= 1; off >>= 1) ls += __shfl_xor(ls, off, 64);
        if (lane == 0) sred[4 + wave] = ls;
        __syncthreads();
        if (t == 0) atomicAdd(ws + S2_OFF + b, sred[4] + sred[5] + sred[6] + sred[7]);
    }
    gg.sync();

    // ---- Phase C: wv = w_sh*invS2; new_mem = mem*(1-wv*e)+wv*a ----
    if (t < M) {
        sm[t]     = sigmoidf(ws[O_OFF + b * L + M + 6 + t]);
        sm[M + t] = ws[O_OFF + b * L + 2 * M + 6 + t];
    }
    __syncthreads();
    {
        const float invS2 = 1.f / (ws[S2_OFF + b] + EPSF);
        float* w_out = out + (size_t)b * N;
        float* m_out = out + (size_t)B * N;
        const int col = (lane & 31) * 4;       // 32 lanes x float4 per row
        const fvec4 ev = *(const fvec4*)&sm[col];
        const fvec4 av = *(const fvec4*)&sm[M + col];
        #pragma unroll 4
        for (int it = 0; it < CHUNK / 8; ++it) {       // 2 rows/wave/iter
            const int n = n0 + wave * (CHUNK / 4) + it * 2 + (lane >> 5);
            const float wv = w_out[n] * invS2;
            const size_t idx = ((size_t)b * N + n) * M + col;
            const fvec4 mv = *(const fvec4*)(mem + idx);
            fvec4 r;
            r.x = fmaf(mv.x, fmaf(-wv, ev.x, 1.f), wv * av.x);
            r.y = fmaf(mv.y, fmaf(-wv, ev.y, 1.f), wv * av.y);
            r.z = fmaf(mv.z, fmaf(-wv, ev.z, 1.f), wv * av.z);
            r.w = fmaf(mv.w, fmaf(-wv, ev.w, 1.f), wv * av.w);
            __builtin_nontemporal_store(r, (fvec4*)(m_out + idx));
            if ((lane & 31) == 0) w_out[n] = wv;
        }
    }
}

// ===========================================================================
// Fallback path (previous 5-kernel pipeline) in case cooperative launch
// is rejected under graph capture.
// ===========================================================================
__global__ __launch_bounds__(256) void k1_gemm(const float* __restrict__ emb,
                                               const float* __restrict__ W,
                                               const float* __restrict__ bias,
                                               float* __restrict__ ws) {
    __shared__ float embS[D];
    __shared__ float red[4][64];
    const int l0 = blockIdx.x * 64;
    const int b  = blockIdx.y;
    const int t  = threadIdx.x;
    for (int i = t; i < D; i += 256) embS[i] = emb[b * D + i];
    __syncthreads();
    const int li = t & 63;
    const int q  = t >> 6;
    const int l  = l0 + li;
    float partial = 0.f;
    if (l < L) {
        const float* wp = W + (size_t)(q * 256) * L + l;
        #pragma unroll 8
        for (int d = 0; d < 256; ++d) partial += embS[q * 256 + d] * wp[(size_t)d * L];
    }
    red[q][li] = partial;
    __syncthreads();
    if (t < 64 && l0 + t < L) {
        float o = red[0][t] + red[1][t] + red[2][t] + red[3][t] + bias[l0 + t];
        ws[O_OFF + b * L + l0 + t] = o;
    }
}

__global__ __launch_bounds__(128) void k1b_act(float* __restrict__ ws) {
    const int b = blockIdx.x;
    const int t = threadIdx.x;
    const float* o = ws + O_OFF + b * L;
    float kv = o[t];
    float sq = kv * kv;
    #pragma unroll
    for (int off = 32; off >= 1; off >>= 1) sq += __shfl_xor(sq, off, 64);
    __shared__ float s01[2];
    if ((t & 63) == 0) s01[t >> 6] = sq;
    __syncthreads();
    if (t == 0) {
        float knorm = sqrtf(s01[0] + s01[1]);
        float beta  = softplusf(o[M]);
        float g     = sigmoidf(o[M + 1]);
        float x0 = o[M + 2], x1 = o[M + 3], x2 = o[M + 4];
        float mx = fmaxf(x0, fmaxf(x1, x2));
        float e0 = expf(x0 - mx), e1 = expf(x1 - mx), e2 = expf(x2 - mx);
        float inv = 1.f / (e0 + e1 + e2);
        float gamma = 1.f + softplusf(o[M + 5]);
        float* p = ws + P_OFF + b * 8;
        p[0] = beta; p[1] = g; p[2] = e0 * inv; p[3] = e1 * inv; p[4] = e2 * inv;
        p[5] = gamma; p[6] = knorm;
        ws[S1_OFF + b] = 0.f;
        ws[S2_OFF + b] = 0.f;
    }
}

__global__ __launch_bounds__(256) void k2_sim(const float* __restrict__ mem,
                                              float* __restrict__ ws) {
    const int b    = blockIdx.y;
    const int n0   = blockIdx.x * 64;
    const int t    = threadIdx.x;
    const int wave = t >> 6, lane = t & 63;
    __shared__ float kS[M];
    if (t < M) kS[t] = ws[O_OFF + b * L + t];
    __syncthreads();
    const float beta  = ws[P_OFF + b * 8 + 0];
    const float knorm = ws[P_OFF + b * 8 + 6];
    float* z = ws + Z_OFF + (size_t)b * N;
    const int seg = (lane & 15) * 8;
    const float4 ka = *(const float4*)&kS[seg];
    const float4 kb = *(const float4*)&kS[seg + 4];
    float lsum = 0.f;
    #pragma unroll
    for (int it = 0; it < 4; ++it) {
        const int n = n0 + wave * 16 + it * 4 + (lane >> 4);
        const float* mp = mem + ((size_t)b * N + n) * M + seg;
        const float4 ma = *(const float4*)mp;
        const float4 mb = *(const float4*)(mp + 4);
        float dot = ma.x*ka.x + ma.y*ka.y + ma.z*ka.z + ma.w*ka.w
                  + mb.x*kb.x + mb.y*kb.y + mb.z*kb.z + mb.w*kb.w;
        float sq  = ma.x*ma.x + ma.y*ma.y + ma.z*ma.z + ma.w*ma.w
                  + mb.x*mb.x + mb.y*mb.y + mb.z*mb.z + mb.w*mb.w;
        #pragma unroll
        for (int off = 1; off <= 8; off <<= 1) {
            dot += __shfl_xor(dot, off, 64);
            sq  += __shfl_xor(sq,  off, 64);
        }
        if ((lane & 15) == 0) {
            const float sim = dot / (sqrtf(sq) * knorm + EPSF);
            const float uu  = expf(beta * sim);
            z[n] = uu;
            lsum += uu;
        }
    }
    lsum += __shfl_xor(lsum, 16, 64);
    lsum += __shfl_xor(lsum, 32, 64);
    __shared__ float acc[4];
    if (lane == 0) acc[wave] = lsum;
    __syncthreads();
    if (t == 0) atomicAdd(ws + S1_OFF + b, acc[0] + acc[1] + acc[2] + acc[3]);
}

__global__ __launch_bounds__(256) void k3_shsum(const float* __restrict__ w_prev,
                                                float* __restrict__ ws,
                                                float* __restrict__ out) {
    const int b = blockIdx.y;
    const int n = blockIdx.x * 256 + threadIdx.x;
    const float* p = ws + P_OFF + b * 8;
    const float g = p[1], s0 = p[2], s1 = p[3], s2 = p[4], gamma = p[5];
    const float invS1 = 1.f / ws[S1_OFF + b];
    const float* u  = ws + Z_OFF + (size_t)b * N;
    const float* wp = w_prev + (size_t)b * N;
    const int nm = (n == 0)     ? N - 1 : n - 1;
    const int np = (n == N - 1) ? 0     : n + 1;
    const float gm1 = 1.f - g;
    const float gi  = g * invS1;
    const float wgm = gi * u[nm] + gm1 * wp[nm];
    const float wg0 = gi * u[n ] + gm1 * wp[n ];
    const float wgp = gi * u[np] + gm1 * wp[np];
    const float wt  = s0 * wgm + s1 * wg0 + s2 * wgp;
    const float v = powf(wt, gamma);
    out[(size_t)b * N + n] = v;
    float r = v;
    #pragma unroll
    for (int off = 32; off >= 1; off >>= 1) r += __shfl_xor(r, off, 64);
    __shared__ float acc[4];
    if ((threadIdx.x & 63) == 0) acc[threadIdx.x >> 6] = r;
    __syncthreads();
    if (threadIdx.x == 0) atomicAdd(ws + S2_OFF + b, acc[0] + acc[1] + acc[2] + acc[3]);
}

__global__ __launch_bounds__(256) void k4_write(const float* __restrict__ mem,
                                                const float* __restrict__ ws,
                                                float* __restrict__ out) {
    const int b    = blockIdx.y;
    const int n0   = (gridDim.x - 1 - blockIdx.x) * 64;
    const int t    = threadIdx.x;
    const int wave = t >> 6, lane = t & 63;
    __shared__ float eS[M], aS[M];
    if (t < M) {
        eS[t] = sigmoidf(ws[O_OFF + b * L + M + 6 + t]);
        aS[t] = ws[O_OFF + b * L + 2 * M + 6 + t];
    }
    __syncthreads();
    const float invS2 = 1.f / (ws[S2_OFF + b] + EPSF);
    float* w_out = out + (size_t)b * N;
    float* m_out = out + (size_t)B * N;
    const int col = (lane & 31) * 4;
    const fvec4 ev = *(const fvec4*)&eS[col];
    const fvec4 av = *(const fvec4*)&aS[col];
    #pragma unroll
    for (int it = 0; it < 8; ++it) {
        const int n = n0 + wave * 16 + it * 2 + (lane >> 5);
        const float wsh = w_out[n];
        const float wv  = wsh * invS2;
        const size_t idx = ((size_t)b * N + n) * M + col;
        const fvec4 mv = *(const fvec4*)(mem + idx);
        fvec4 r;
        r.x = fmaf(mv.x, fmaf(-wv, ev.x, 1.f), wv * av.x);
        r.y = fmaf(mv.y, fmaf(-wv, ev.y, 1.f), wv * av.y);
        r.z = fmaf(mv.z, fmaf(-wv, ev.z, 1.f), wv * av.z);
        r.w = fmaf(mv.w, fmaf(-wv, ev.w, 1.f), wv * av.w);
        __builtin_nontemporal_store(r, (fvec4*)(m_out + idx));
        if ((lane & 31) == 0)
            __builtin_nontemporal_store(wv, w_out + n);
    }
}

extern "C" void kernel_launch(void* const* d_in, const int* in_sizes, int n_in,
                              void* d_out, int out_size, void* d_ws, size_t ws_size,
                              hipStream_t stream) {
    const float* emb    = (const float*)d_in[0];
    const float* w_prev = (const float*)d_in[1];
    const float* mem    = (const float*)d_in[2];
    const float* W      = (const float*)d_in[3];
    const float* bias   = (const float*)d_in[4];
    float* ws  = (float*)d_ws;    // needs (B*L + B*8 + 2*B + B*N)*4 ≈ 2.15 MB
    float* out = (float*)d_out;

    void* args[] = {(void*)&emb, (void*)&w_prev, (void*)&mem, (void*)&W,
                    (void*)&bias, (void*)&ws, (void*)&out};
    hipError_t err = hipLaunchCooperativeKernel((const void*)fused_all,
                                                dim3(GRID), dim3(256),
                                                args, 0, stream);
    if (err != hipSuccess) {
        // Fallback: previous 5-kernel pipeline.
        k1_gemm <<<dim3(7, B),       256, 0, stream>>>(emb, W, bias, ws);
        k1b_act <<<dim3(B),          128, 0, stream>>>(ws);
        k2_sim  <<<dim3(N / 64, B),  256, 0, stream>>>(mem, ws);
        k3_shsum<<<dim3(N / 256, B), 256, 0, stream>>>(w_prev, ws, out);
        k4_write<<<dim3(N / 64, B),  256, 0, stream>>>(mem, ws, out);
    }
}

// Round 3
// 536.481 us; speedup vs baseline: 1.8116x; 1.8116x over previous
//
#include <hip/hip_runtime.h>
#include <math.h>

#define B 32
#define N 16384
#define M 128
#define D 1024
#define L 390   // 3*M+6
#define EPSF 1e-16f

// ws layout (floats):
//   [O_OFF,  O_OFF+B*L)   o = emb@W + b
//   [P_OFF,  P_OFF+B*8)   per-batch params {beta,g,s0,s1,s2,gamma,knorm,pad}
//   [S1_OFF, +B)          sum exp(z)   (atomic)
//   [S2_OFF, +B)          sum w_sh     (atomic)
//   [Z_OFF,  +B*N)        u = exp(beta*sim)
#define O_OFF  0
#define P_OFF  (B*L)
#define S1_OFF (P_OFF + B*8)
#define S2_OFF (S1_OFF + B)
#define Z_OFF  (S2_OFF + B)

typedef float fvec4 __attribute__((ext_vector_type(4)));

__device__ __forceinline__ float softplusf(float x) {
    return x > 20.f ? x : log1pf(expf(x));
}
__device__ __forceinline__ float sigmoidf(float x) {
    return 1.f / (1.f + expf(-x));
}

// K1: o[b, l0:l0+64] = emb[b,:] @ W[:, l0:l0+64] + bias.  grid(7, B), 256 thr.
__global__ __launch_bounds__(256) void k1_gemm(const float* __restrict__ emb,
                                               const float* __restrict__ W,
                                               const float* __restrict__ bias,
                                               float* __restrict__ ws) {
    __shared__ float embS[D];
    __shared__ float red[4][64];
    const int l0 = blockIdx.x * 64;
    const int b  = blockIdx.y;
    const int t  = threadIdx.x;
    for (int i = t; i < D; i += 256) embS[i] = emb[b * D + i];
    __syncthreads();
    const int li = t & 63;
    const int q  = t >> 6;          // 4-way split of the D dimension
    const int l  = l0 + li;
    float partial = 0.f;
    if (l < L) {
        const float* wp = W + (size_t)(q * 256) * L + l;
        #pragma unroll 8
        for (int d = 0; d < 256; ++d) partial += embS[q * 256 + d] * wp[(size_t)d * L];
    }
    red[q][li] = partial;
    __syncthreads();
    if (t < 64 && l0 + t < L) {
        float o = red[0][t] + red[1][t] + red[2][t] + red[3][t] + bias[l0 + t];
        ws[O_OFF + b * L + l0 + t] = o;
    }
}

// K1b: per-batch scalar params + zero atomics. grid(B), 128 thr.
__global__ __launch_bounds__(128) void k1b_act(float* __restrict__ ws) {
    const int b = blockIdx.x;
    const int t = threadIdx.x;                 // 128 threads = 2 waves
    const float* o = ws + O_OFF + b * L;
    float kv = o[t];
    float sq = kv * kv;
    #pragma unroll
    for (int off = 32; off >= 1; off >>= 1) sq += __shfl_xor(sq, off, 64);
    __shared__ float s01[2];
    if ((t & 63) == 0) s01[t >> 6] = sq;
    __syncthreads();
    if (t == 0) {
        float knorm = sqrtf(s01[0] + s01[1]);
        float beta  = softplusf(o[M]);
        float g     = sigmoidf(o[M + 1]);
        float x0 = o[M + 2], x1 = o[M + 3], x2 = o[M + 4];
        float mx = fmaxf(x0, fmaxf(x1, x2));
        float e0 = expf(x0 - mx), e1 = expf(x1 - mx), e2 = expf(x2 - mx);
        float inv = 1.f / (e0 + e1 + e2);
        float gamma = 1.f + softplusf(o[M + 5]);
        float* p = ws + P_OFF + b * 8;
        p[0] = beta; p[1] = g; p[2] = e0 * inv; p[3] = e1 * inv; p[4] = e2 * inv;
        p[5] = gamma; p[6] = knorm;
        ws[S1_OFF + b] = 0.f;
        ws[S2_OFF + b] = 0.f;
    }
}

// K2: u[b,n] = exp(beta*cos_sim(mem[b,n,:],k)); atomic S1 += sum u.
// ROW-PER-LANE: each lane owns one full row (32 x float4 independent loads,
// k broadcast from LDS). No cross-lane ops, no divergence in the hot loop ->
// nothing blocks load pipelining; u store is wave-coalesced.
// grid(N/256, B), 256 thr.
__global__ __launch_bounds__(256) void k2_sim(const float* __restrict__ mem,
                                              float* __restrict__ ws) {
    const int b = blockIdx.y;
    const int t = threadIdx.x;
    const int n = blockIdx.x * 256 + t;
    const int wave = t >> 6, lane = t & 63;
    __shared__ float kS[M];
    if (t < M) kS[t] = ws[O_OFF + b * L + t];
    __syncthreads();
    const float beta  = ws[P_OFF + b * 8 + 0];
    const float knorm = ws[P_OFF + b * 8 + 6];
    const float* mp = mem + ((size_t)b * N + n) * M;

    float dot = 0.f, sq = 0.f;
    #pragma unroll 16
    for (int j = 0; j < M / 4; ++j) {
        const fvec4 mv = *(const fvec4*)(mp + j * 4);
        const fvec4 kv = *(const fvec4*)&kS[j * 4];     // LDS broadcast
        dot = fmaf(mv.x, kv.x, dot); dot = fmaf(mv.y, kv.y, dot);
        dot = fmaf(mv.z, kv.z, dot); dot = fmaf(mv.w, kv.w, dot);
        sq  = fmaf(mv.x, mv.x, sq);  sq  = fmaf(mv.y, mv.y, sq);
        sq  = fmaf(mv.z, mv.z, sq);  sq  = fmaf(mv.w, mv.w, sq);
    }
    const float sim = dot / (sqrtf(sq) * knorm + EPSF);
    const float uu  = expf(beta * sim);
    ws[Z_OFF + (size_t)b * N + n] = uu;        // fully coalesced store

    // block reduction -> S1
    float r = uu;
    #pragma unroll
    for (int off = 32; off >= 1; off >>= 1) r += __shfl_xor(r, off, 64);
    __shared__ float acc[4];
    if (lane == 0) acc[wave] = r;
    __syncthreads();
    if (t == 0) atomicAdd(ws + S1_OFF + b, acc[0] + acc[1] + acc[2] + acc[3]);
}

// K3: w_sh[b,n] = (s0*wg(n-1)+s1*wg(n)+s2*wg(n+1))^gamma, stash into out's w
// region; atomic S2 += sum.  grid(N/256, B).
__global__ __launch_bounds__(256) void k3_shsum(const float* __restrict__ w_prev,
                                                float* __restrict__ ws,
                                                float* __restrict__ out) {
    const int b = blockIdx.y;
    const int n = blockIdx.x * 256 + threadIdx.x;
    const float* p = ws + P_OFF + b * 8;
    const float g = p[1], s0 = p[2], s1 = p[3], s2 = p[4], gamma = p[5];
    const float invS1 = 1.f / ws[S1_OFF + b];
    const float* u  = ws + Z_OFF + (size_t)b * N;
    const float* wp = w_prev + (size_t)b * N;
    const int nm = (n == 0)     ? N - 1 : n - 1;
    const int np = (n == N - 1) ? 0     : n + 1;
    const float gm1 = 1.f - g;
    const float gi  = g * invS1;
    const float wgm = gi * u[nm] + gm1 * wp[nm];
    const float wg0 = gi * u[n ] + gm1 * wp[n ];
    const float wgp = gi * u[np] + gm1 * wp[np];
    const float wt  = s0 * wgm + s1 * wg0 + s2 * wgp;
    const float v = powf(wt, gamma);
    out[(size_t)b * N + n] = v;                // stash w_sh; k4 scales by invS2
    float r = v;
    #pragma unroll
    for (int off = 32; off >= 1; off >>= 1) r += __shfl_xor(r, off, 64);
    __shared__ float acc[4];
    if ((threadIdx.x & 63) == 0) acc[threadIdx.x >> 6] = r;
    __syncthreads();
    if (threadIdx.x == 0) atomicAdd(ws + S2_OFF + b, acc[0] + acc[1] + acc[2] + acc[3]);
}

// K4: wv = w_sh[n]*invS2 (finalize w); new_mem = mem*(1-wv*e)+wv*a.
// ALIAS-FREE PIPELINING: all 8 w_sh values preloaded into registers BEFORE
// the first store (w_sh and new_mem both live in `out`, so interleaved
// load/store serializes on the may-alias check). mem loads come from a
// distinct restrict pointer -> all 8 stay in flight above the NT stores.
// Reversed traversal + NT stores keep mem's L3 residency from k2.
// grid(N/64, B), 256 thr = 4 waves, 16 rows/wave.
__global__ __launch_bounds__(256) void k4_write(const float* __restrict__ mem,
                                                const float* __restrict__ ws,
                                                float* __restrict__ out) {
    const int b    = blockIdx.y;
    const int n0   = (gridDim.x - 1 - blockIdx.x) * 64;   // reversed traversal
    const int t    = threadIdx.x;
    const int wave = t >> 6, lane = t & 63;
    __shared__ float eS[M], aS[M];
    if (t < M) {
        eS[t] = sigmoidf(ws[O_OFF + b * L + M + 6 + t]);
        aS[t] = ws[O_OFF + b * L + 2 * M + 6 + t];
    }
    __syncthreads();
    const float invS2 = 1.f / (ws[S2_OFF + b] + EPSF);
    float* w_out = out + (size_t)b * N;
    float* m_out = out + (size_t)B * N;
    const int col  = (lane & 31) * 4;
    const int half = lane >> 5;
    const int base = n0 + wave * 16;
    const fvec4 ev = *(const fvec4*)&eS[col];
    const fvec4 av = *(const fvec4*)&aS[col];

    // preload all w_sh for this wave's 16 rows (before any store to `out`)
    float wv[8];
    #pragma unroll
    for (int it = 0; it < 8; ++it)
        wv[it] = w_out[base + it * 2 + half] * invS2;

    #pragma unroll
    for (int it = 0; it < 8; ++it) {
        const int n = base + it * 2 + half;
        const size_t idx = ((size_t)b * N + n) * M + col;
        const fvec4 mv = __builtin_nontemporal_load((const fvec4*)(mem + idx));
        const float w = wv[it];
        fvec4 r;
        r.x = fmaf(mv.x, fmaf(-w, ev.x, 1.f), w * av.x);
        r.y = fmaf(mv.y, fmaf(-w, ev.y, 1.f), w * av.y);
        r.z = fmaf(mv.z, fmaf(-w, ev.z, 1.f), w * av.z);
        r.w = fmaf(mv.w, fmaf(-w, ev.w, 1.f), w * av.w);
        __builtin_nontemporal_store(r, (fvec4*)(m_out + idx));
    }

    // finalize w (tiny region: plain cached stores, full lines form in L2)
    if ((lane & 31) == 0) {
        #pragma unroll
        for (int it = 0; it < 8; ++it)
            w_out[base + it * 2 + half] = wv[it];
    }
}

extern "C" void kernel_launch(void* const* d_in, const int* in_sizes, int n_in,
                              void* d_out, int out_size, void* d_ws, size_t ws_size,
                              hipStream_t stream) {
    const float* emb    = (const float*)d_in[0];
    const float* w_prev = (const float*)d_in[1];
    const float* mem    = (const float*)d_in[2];
    const float* W      = (const float*)d_in[3];
    const float* bias   = (const float*)d_in[4];
    float* ws  = (float*)d_ws;    // needs (B*L + B*8 + 2*B + B*N)*4 ≈ 2.15 MB
    float* out = (float*)d_out;

    k1_gemm <<<dim3(7, B),       256, 0, stream>>>(emb, W, bias, ws);
    k1b_act <<<dim3(B),          128, 0, stream>>>(ws);
    k2_sim  <<<dim3(N / 256, B), 256, 0, stream>>>(mem, ws);
    k3_shsum<<<dim3(N / 256, B), 256, 0, stream>>>(w_prev, ws, out);
    k4_write<<<dim3(N / 64, B),  256, 0, stream>>>(mem, ws, out);
}